// Round 1
// baseline (83.608 us; speedup 1.0000x reference)
//
#include <hip/hip_runtime.h>
#include <math.h>

// HypAgg: hyperbolic (Poincare ball, c=1) attention aggregation.
// Factored form:
//   sub_ij = (-alpha_ij x_i + beta_i x_j)/den_ij
//   g_ij   = att_ij * atanh(sn_ij)/sn_ij / den_ij
//   support_i = beta_i * ( -S_i x_i + beta_i Y_i ),  S=sum g*alpha, Y=sum g x_j
// ws layout (floats): Y[1024*128] | S[1024] | x2[1024] | L[1024] | R[1024]  (~541KB)

typedef short short4v __attribute__((ext_vector_type(4)));
typedef short short8v __attribute__((ext_vector_type(8)));
typedef float float4v __attribute__((ext_vector_type(4)));

static __device__ __forceinline__ short f2bf(float f) {
    unsigned u = __float_as_uint(f);
    u += 0x7fff + ((u >> 16) & 1);   // RNE; inputs never NaN here
    return (short)(u >> 16);
}
static __device__ __forceinline__ float rcpf(float x) { return __builtin_amdgcn_rcpf(x); }

// ---------------- kernel 1: per-row stats (x2, L, R) ----------------
__global__ __launch_bounds__(256) void hyp_stats(
    const float* __restrict__ x, const float* __restrict__ w,
    float* __restrict__ st_x2, float* __restrict__ st_L, float* __restrict__ st_R)
{
    int row  = blockIdx.x * 4 + (threadIdx.x >> 6);
    int lane = threadIdx.x & 63;
    const float* xr = x + row * 128;
    float a0 = xr[lane], a1 = xr[lane + 64];
    float x2 = a0 * a0 + a1 * a1;
    float dl = a0 * w[lane]       + a1 * w[lane + 64];
    float dr = a0 * w[lane + 128] + a1 * w[lane + 192];
    for (int m = 1; m < 64; m <<= 1) {
        x2 += __shfl_xor(x2, m);
        dl += __shfl_xor(dl, m);
        dr += __shfl_xor(dr, m);
    }
    if (lane == 0) {
        float pn = sqrtf(fmaxf(x2, 1e-15f));
        float uu = fminf(pn, 1.f - 1e-7f);
        float at = 0.5f * __logf((1.f + uu) * rcpf(1.f - uu));  // atanh
        float f  = at * rcpf(pn);                                // logmap0 scale
        st_x2[row] = x2;
        st_L[row]  = f * dl;
        st_R[row]  = f * dr;
    }
}

// ---------------- kernel 2: pairwise MFMA + scalar map + aggregate ----------------
// grid (64, 4): blockIdx.x -> 16-row i-tile, blockIdx.y -> 256-col j-chunk.
__global__ __launch_bounds__(256) void hyp_main(
    const float* __restrict__ x, const float* __restrict__ adj,
    const float* __restrict__ battp,
    const float* __restrict__ st_x2, const float* __restrict__ st_L,
    const float* __restrict__ st_R,
    float* __restrict__ Y, float* __restrict__ Sg)
{
    __shared__ unsigned short sXI[16 * 132];   // bf16, pitch 132 shorts
    __shared__ unsigned short sXJ[128 * 132];  // bf16, one 128-row half at a time
    __shared__ unsigned short sW [16 * 132];   // bf16 g weights
    __shared__ float sAdj[16 * 129];
    __shared__ float sX2J[128], sRJ[128];
    __shared__ float sX2I[16], sLI[16], sBI[16];
    __shared__ float sS[16];

    const int t    = threadIdx.x;
    const int lane = t & 63;
    const int wave = t >> 6;
    const int n    = lane & 15;   // mfma 16-col lane
    const int q    = lane >> 4;   // quad
    const int i0   = blockIdx.x * 16;
    const int j0   = blockIdx.y * 256;
    const float batt = battp[0];

    if (t < 16) {
        float v = st_x2[i0 + t];
        sX2I[t] = v; sBI[t] = 1.f - v; sLI[t] = st_L[i0 + t];
        sS[t] = 0.f;
    }
    // stage X_I (16 rows x 128) fp32 -> bf16
    for (int idx = t; idx < 16 * 32; idx += 256) {
        int r = idx >> 5, c = idx & 31;
        float4v v = ((const float4v*)x)[(i0 + r) * 32 + c];
        short4v h = { f2bf(v[0]), f2bf(v[1]), f2bf(v[2]), f2bf(v[3]) };
        *(short4v*)&sXI[r * 132 + c * 4] = h;
    }
    __syncthreads();

    // per-lane i stats (i = q*4+r) and preloaded A-frags (X_I rows, A[m=lane&15][k=q*8+e])
    float x2i4[4], bi4[4], li4[4];
    for (int r = 0; r < 4; ++r) {
        int i = q * 4 + r;
        x2i4[r] = sX2I[i]; bi4[r] = sBI[i]; li4[r] = sLI[i];
    }
    short8v afrag[4];
    for (int kk = 0; kk < 4; ++kk) {
        const unsigned short* p = &sXI[n * 132 + kk * 32 + q * 8];
        short4v lo = *(const short4v*)p;
        short4v hi = *(const short4v*)(p + 4);
        afrag[kk] = (short8v){ lo[0], lo[1], lo[2], lo[3], hi[0], hi[1], hi[2], hi[3] };
    }

    float4v accB[2];
    accB[0] = (float4v){0.f, 0.f, 0.f, 0.f};
    accB[1] = (float4v){0.f, 0.f, 0.f, 0.f};
    float Sacc[4] = {0.f, 0.f, 0.f, 0.f};

    for (int half = 0; half < 2; ++half) {
        const int jh = j0 + half * 128;
        __syncthreads();   // protect sXJ/sAdj restage vs previous half's reads
        for (int idx = t; idx < 128 * 32; idx += 256) {
            int r = idx >> 5, c = idx & 31;
            float4v v = ((const float4v*)x)[(jh + r) * 32 + c];
            short4v h = { f2bf(v[0]), f2bf(v[1]), f2bf(v[2]), f2bf(v[3]) };
            *(short4v*)&sXJ[r * 132 + c * 4] = h;
        }
        for (int idx = t; idx < 16 * 32; idx += 256) {
            int r = idx >> 5, c = idx & 31;
            float4v v = ((const float4v*)adj)[(i0 + r) * 256 + (jh >> 2) + c];
            float* d = &sAdj[r * 129 + c * 4];
            d[0] = v[0]; d[1] = v[1]; d[2] = v[2]; d[3] = v[3];
        }
        if (t < 128) { sX2J[t] = st_x2[jh + t]; sRJ[t] = st_R[jh + t]; }
        __syncthreads();

        // ---- phase A: G = X_I * X_J^T (this half), + per-pair scalar map -> sW
        for (int jsl = 0; jsl < 2; ++jsl) {
            int js = wave * 2 + jsl;              // 8 subtiles of 16 j
            int jrow = js * 16 + n;
            float4v acc = (float4v){0.f, 0.f, 0.f, 0.f};
            for (int kk = 0; kk < 4; ++kk) {
                const unsigned short* p = &sXJ[jrow * 132 + kk * 32 + q * 8];
                short4v lo = *(const short4v*)p;
                short4v hi = *(const short4v*)(p + 4);
                short8v b = (short8v){ lo[0], lo[1], lo[2], lo[3], hi[0], hi[1], hi[2], hi[3] };
                acc = __builtin_amdgcn_mfma_f32_16x16x32_bf16(afrag[kk], b, acc, 0, 0, 0);
            }
            // lane holds G[i=q*4+r][j=js*16+n]   (C layout: col=lane&15, row=quad*4+reg)
            float x2j = sX2J[js * 16 + n];
            float rj  = sRJ[js * 16 + n];
            for (int r = 0; r < 4; ++r) {
                float G    = acc[r];
                int   i    = q * 4 + r;
                float adjv = sAdj[i * 129 + js * 16 + n];
                float alpha = 1.f - 2.f * G + x2j;
                float den   = fmaxf(fmaf(x2i4[r], x2j, 1.f - 2.f * G), 1e-15f);
                float rdn   = rcpf(den);
                float bb    = bi4[r];
                float nn2   = alpha * alpha * x2i4[r] + bb * bb * x2j - 2.f * alpha * bb * G;
                float sub2  = nn2 * rdn * rdn;
                float sn    = sqrtf(fmaxf(sub2, 1e-15f));
                float uu    = fminf(sn, 1.f - 1e-7f);
                float at    = 0.5f * __logf((1.f + uu) * rcpf(1.f - uu));  // atanh(uu)
                float tt    = at * rcpf(sn);
                float z     = li4[r] + rj + batt;
                float sig   = rcpf(1.f + __expf(-z));
                float g     = sig * adjv * tt * rdn;
                Sacc[r]     = fmaf(g, alpha, Sacc[r]);
                sW[i * 132 + js * 16 + n] = (unsigned short)f2bf(g);
            }
        }
        __syncthreads();

        // ---- phase B: acc += W(16x128) * X_J(128x128), K = this half's j range
        for (int nsl = 0; nsl < 2; ++nsl) {
            int ns = wave * 2 + nsl;              // 8 subtiles of 16 dims
            for (int kk = 0; kk < 4; ++kk) {
                const unsigned short* pa = &sW[n * 132 + kk * 32 + q * 8];
                short4v lo = *(const short4v*)pa;
                short4v hi = *(const short4v*)(pa + 4);
                short8v a = (short8v){ lo[0], lo[1], lo[2], lo[3], hi[0], hi[1], hi[2], hi[3] };
                short8v b;
                int kbase = kk * 32 + q * 8;
#pragma unroll
                for (int e = 0; e < 8; ++e)
                    b[e] = (short)sXJ[(kbase + e) * 132 + ns * 16 + n];
                accB[nsl] = __builtin_amdgcn_mfma_f32_16x16x32_bf16(a, b, accB[nsl], 0, 0, 0);
            }
        }
    }

    // ---- epilogue: S reduction + global atomics
    for (int r = 0; r < 4; ++r) {
        float v = Sacc[r];
        v += __shfl_xor(v, 1); v += __shfl_xor(v, 2);
        v += __shfl_xor(v, 4); v += __shfl_xor(v, 8);
        if (n == 0) atomicAdd(&sS[q * 4 + r], v);
    }
    for (int nsl = 0; nsl < 2; ++nsl) {
        int ns = wave * 2 + nsl;
        for (int r = 0; r < 4; ++r)
            atomicAdd(&Y[(i0 + q * 4 + r) * 128 + ns * 16 + n], accB[nsl][r]);
    }
    __syncthreads();
    if (t < 16) atomicAdd(&Sg[i0 + t], sS[t]);
}

// ---------------- kernel 3: expmap epilogue ----------------
__global__ __launch_bounds__(256) void hyp_exp(
    const float* __restrict__ x, const float* __restrict__ Y,
    const float* __restrict__ Sg, const float* __restrict__ st_x2,
    float* __restrict__ out)
{
    int i    = blockIdx.x * 4 + (threadIdx.x >> 6);
    int lane = threadIdx.x & 63;
    float x0 = x[i * 128 + lane], x1 = x[i * 128 + 64 + lane];
    float y0 = Y[i * 128 + lane], y1 = Y[i * 128 + 64 + lane];
    float S  = Sg[i];
    float x2 = st_x2[i];
    float b  = fmaxf(1.f - x2, 1e-15f);
    float u0 = b * (b * y0 - S * x0);
    float u1 = b * (b * y1 - S * x1);
    float un2 = u0 * u0 + u1 * u1;
    float xu  = x0 * u0 + x1 * u1;
    for (int m = 1; m < 64; m <<= 1) {
        un2 += __shfl_xor(un2, m);
        xu  += __shfl_xor(xu, m);
    }
    float un  = sqrtf(fmaxf(un2, 1e-15f));
    float th  = tanhf(un * rcpf(b));
    float s2  = th * rcpf(un);         // tanh(un/b)/un
    float xy  = s2 * xu;               // <x, second>
    float y2s = th * th;               // ||second||^2
    float coef = 1.f + 2.f * xy + y2s;
    float den  = fmaxf(1.f + 2.f * xy + x2 * y2s, 1e-15f);
    float rd   = rcpf(den);
    out[i * 128 + lane]      = (coef * x0 + b * (s2 * u0)) * rd;
    out[i * 128 + 64 + lane] = (coef * x1 + b * (s2 * u1)) * rd;
}

extern "C" void kernel_launch(void* const* d_in, const int* in_sizes, int n_in,
                              void* d_out, int out_size, void* d_ws, size_t ws_size,
                              hipStream_t stream) {
    const float* x    = (const float*)d_in[0];
    const float* adj  = (const float*)d_in[1];
    const float* w    = (const float*)d_in[2];
    const float* batt = (const float*)d_in[3];
    float* out = (float*)d_out;

    float* Y     = (float*)d_ws;        // 1024*128
    float* Sg    = Y + 131072;          // 1024
    float* st_x2 = Sg + 1024;           // 1024
    float* st_L  = st_x2 + 1024;        // 1024
    float* st_R  = st_L + 1024;         // 1024

    // zero the atomic accumulators (ws is poisoned 0xAA before every launch)
    hipMemsetAsync(d_ws, 0, (131072 + 1024) * sizeof(float), stream);
    hipLaunchKernelGGL(hyp_stats, dim3(256), dim3(256), 0, stream, x, w, st_x2, st_L, st_R);
    hipLaunchKernelGGL(hyp_main, dim3(64, 4), dim3(256), 0, stream,
                       x, adj, batt, st_x2, st_L, st_R, Y, Sg);
    hipLaunchKernelGGL(hyp_exp, dim3(256), dim3(256), 0, stream, x, Y, Sg, st_x2, out);
}

// Round 2
// 73.289 us; speedup vs baseline: 1.1408x; 1.1408x over previous
//
#include <hip/hip_runtime.h>
#include <math.h>

// HypAgg (Poincare ball, c=1) factored:
//   g_ij = att_ij * atanh(sn_ij)/sn_ij / den_ij
//   support_i = beta_i * ( -S_i x_i + beta_i Y_i ),  S=sum g*alpha, Y=sum g x_j
// Grid: hyp_main (64 i-tiles x 8 j-chunks of 128). No atomics: per-chunk
// partials Yp/Sp summed in hyp_exp.
// ws floats: Yp[8*131072] | Sp[8*1024] | st_x2[1024] | st_L[1024] | st_R[1024]

typedef short short4v __attribute__((ext_vector_type(4)));
typedef short short8v __attribute__((ext_vector_type(8)));
typedef float float4v __attribute__((ext_vector_type(4)));

static __device__ __forceinline__ short f2bf(float f) {
    unsigned u = __float_as_uint(f);
    u += 0x7fff + ((u >> 16) & 1);   // RNE; inputs never NaN here
    return (short)(u >> 16);
}
static __device__ __forceinline__ float rcpf(float x) { return __builtin_amdgcn_rcpf(x); }
static __device__ __forceinline__ short8v ld8(const unsigned short* p) {
    short4v lo = *(const short4v*)p;        // 8B-aligned LDS reads (pitch 132 shorts)
    short4v hi = *(const short4v*)(p + 4);
    return (short8v){lo[0],lo[1],lo[2],lo[3],hi[0],hi[1],hi[2],hi[3]};
}

// ---------------- kernel 1: per-row stats (x2, L, R) ----------------
__global__ __launch_bounds__(256) void hyp_stats(
    const float* __restrict__ x, const float* __restrict__ w,
    float* __restrict__ st_x2, float* __restrict__ st_L, float* __restrict__ st_R)
{
    int row  = blockIdx.x * 4 + (threadIdx.x >> 6);
    int lane = threadIdx.x & 63;
    const float* xr = x + row * 128;
    float a0 = xr[lane], a1 = xr[lane + 64];
    float x2 = a0 * a0 + a1 * a1;
    float dl = a0 * w[lane]       + a1 * w[lane + 64];
    float dr = a0 * w[lane + 128] + a1 * w[lane + 192];
    for (int m = 1; m < 64; m <<= 1) {
        x2 += __shfl_xor(x2, m);
        dl += __shfl_xor(dl, m);
        dr += __shfl_xor(dr, m);
    }
    if (lane == 0) {
        float pn = sqrtf(fmaxf(x2, 1e-15f));
        float uu = fminf(pn, 1.f - 1e-7f);
        float at = 0.5f * __logf((1.f + uu) * rcpf(1.f - uu));  // atanh
        float f  = at * rcpf(pn);                                // logmap0 scale
        st_x2[row] = x2;
        st_L[row]  = f * dl;
        st_R[row]  = f * dr;
    }
}

// ---------------- kernel 2: pairwise MFMA + scalar map + aggregate ----------------
__global__ __launch_bounds__(256, 2) void hyp_main(
    const float* __restrict__ x, const float* __restrict__ adj,
    const float* __restrict__ battp,
    const float* __restrict__ st_x2, const float* __restrict__ st_L,
    const float* __restrict__ st_R,
    float* __restrict__ Yp, float* __restrict__ Sp)
{
    __shared__ unsigned short sXI [16 * 132];   // X_I  bf16, row-major (i, dim)
    __shared__ unsigned short sXJ [128 * 132];  // X_J  bf16, row-major (j, dim)
    __shared__ unsigned short sXJt[128 * 132];  // X_J^T bf16, (dim, j)
    __shared__ unsigned short sW  [16 * 132];   // g weights bf16, (i, j)
    __shared__ float sS[16];

    const int t    = threadIdx.x;
    const int lane = t & 63;
    const int wave = t >> 6;
    const int n    = lane & 15;   // mfma 16-col lane
    const int q    = lane >> 4;   // quad
    const int i0   = blockIdx.x * 16;
    const int c    = blockIdx.y;      // j-chunk
    const int j0   = c * 128;
    const float batt = battp[0];

    // ---- register prefetch (independent of LDS; hidden behind staging) ----
    float x2i4[4], bi4[4], li4[4];
#pragma unroll
    for (int r = 0; r < 4; ++r) {
        int i = i0 + q * 4 + r;
        x2i4[r] = st_x2[i];
        li4[r]  = st_L[i];
    }
    float x2j2[2], rj2[2], adjv[2][4];
#pragma unroll
    for (int jsl = 0; jsl < 2; ++jsl) {
        int j = j0 + (wave * 2 + jsl) * 16 + n;
        x2j2[jsl] = st_x2[j];
        rj2[jsl]  = st_R[j];
#pragma unroll
        for (int r = 0; r < 4; ++r)
            adjv[jsl][r] = adj[(i0 + q * 4 + r) * 1024 + j];
    }
#pragma unroll
    for (int r = 0; r < 4; ++r) bi4[r] = 1.f - x2i4[r];

    if (t < 16) sS[t] = 0.f;

    // ---- stage X_I (16x128) fp32 -> bf16 ----
    for (int idx = t; idx < 16 * 32; idx += 256) {
        int r = idx >> 5, cc = idx & 31;
        float4v v = ((const float4v*)x)[(i0 + r) * 32 + cc];
        short4v h = { f2bf(v[0]), f2bf(v[1]), f2bf(v[2]), f2bf(v[3]) };
        *(short4v*)&sXI[r * 132 + cc * 4] = h;
    }
    // ---- stage X_J both layouts via 4x4 micro-blocks ----
    // bid bits: [0..3]=dcL, [4..5]=jrL, [6..8]=jrH, [9]=dcH
    // (keeps global coalesced: per wave 4 rows x 256B; LDS writes <=4-way)
#pragma unroll
    for (int it = 0; it < 4; ++it) {
        int bid = t + it * 256;
        int jr = ((bid >> 4) & 3) | (((bid >> 6) & 7) << 2);   // 0..31
        int dc = (bid & 15) | (((bid >> 9) & 1) << 4);         // 0..31
        float4v v[4];
#pragma unroll
        for (int e = 0; e < 4; ++e)
            v[e] = ((const float4v*)x)[(j0 + jr * 4 + e) * 32 + dc];
        short4v h[4];
#pragma unroll
        for (int e = 0; e < 4; ++e) {
            h[e] = (short4v){ f2bf(v[e][0]), f2bf(v[e][1]), f2bf(v[e][2]), f2bf(v[e][3]) };
            *(short4v*)&sXJ[(jr * 4 + e) * 132 + dc * 4] = h[e];
        }
#pragma unroll
        for (int d = 0; d < 4; ++d) {
            short4v ht = (short4v){ h[0][d], h[1][d], h[2][d], h[3][d] };
            *(short4v*)&sXJt[(dc * 4 + d) * 132 + jr * 4] = ht;
        }
    }
    __syncthreads();

    // A-frags: X_I rows, A[m=lane&15][k=q*8+e]
    short8v afrag[4];
#pragma unroll
    for (int kk = 0; kk < 4; ++kk)
        afrag[kk] = ld8(&sXI[n * 132 + kk * 32 + q * 8]);

    float Sacc[4] = {0.f, 0.f, 0.f, 0.f};

    // ---- phase A: G = X_I * X_J^T, per-pair scalar map -> sW ----
#pragma unroll
    for (int jsl = 0; jsl < 2; ++jsl) {
        int js = wave * 2 + jsl;              // 8 subtiles of 16 j
        int jrow = js * 16 + n;
        float4v acc = (float4v){0.f, 0.f, 0.f, 0.f};
#pragma unroll
        for (int kk = 0; kk < 4; ++kk) {
            short8v b = ld8(&sXJ[jrow * 132 + kk * 32 + q * 8]);
            acc = __builtin_amdgcn_mfma_f32_16x16x32_bf16(afrag[kk], b, acc, 0, 0, 0);
        }
        // lane holds G[i=q*4+r][j=js*16+n]
        float x2j = x2j2[jsl];
        float rj  = rj2[jsl];
#pragma unroll
        for (int r = 0; r < 4; ++r) {
            float G     = acc[r];
            int   i     = q * 4 + r;
            float alpha = 1.f - 2.f * G + x2j;
            float den   = fmaxf(fmaf(x2i4[r], x2j, 1.f - 2.f * G), 1e-15f);
            float rdn   = rcpf(den);
            float bb    = bi4[r];
            float nn2   = alpha * alpha * x2i4[r] + bb * bb * x2j - 2.f * alpha * bb * G;
            float sub2  = nn2 * rdn * rdn;
            float sn    = sqrtf(fmaxf(sub2, 1e-15f));
            float uu    = fminf(sn, 1.f - 1e-7f);
            float at    = 0.5f * __logf((1.f + uu) * rcpf(1.f - uu));  // atanh(uu)
            float tt    = at * rcpf(sn);
            float z     = li4[r] + rj + batt;
            float sig   = rcpf(1.f + __expf(-z));
            float g     = sig * adjv[jsl][r] * tt * rdn;
            Sacc[r]     = fmaf(g, alpha, Sacc[r]);
            sW[i * 132 + js * 16 + n] = (unsigned short)f2bf(g);
        }
    }
    __syncthreads();

    // ---- phase B: Y = W(16x128) * X_J(128x128), B-frags contiguous from sXJt ----
    float4v accB[2];
    accB[0] = (float4v){0.f, 0.f, 0.f, 0.f};
    accB[1] = (float4v){0.f, 0.f, 0.f, 0.f};
#pragma unroll
    for (int nsl = 0; nsl < 2; ++nsl) {
        int ns = wave * 2 + nsl;              // 8 subtiles of 16 dims
#pragma unroll
        for (int kk = 0; kk < 4; ++kk) {
            short8v a = ld8(&sW  [n * 132 + kk * 32 + q * 8]);
            short8v b = ld8(&sXJt[(ns * 16 + n) * 132 + kk * 32 + q * 8]);
            accB[nsl] = __builtin_amdgcn_mfma_f32_16x16x32_bf16(a, b, accB[nsl], 0, 0, 0);
        }
    }

    // ---- epilogue: S reduce + partial stores (no atomics to global) ----
#pragma unroll
    for (int r = 0; r < 4; ++r) {
        float v = Sacc[r];
        v += __shfl_xor(v, 1); v += __shfl_xor(v, 2);
        v += __shfl_xor(v, 4); v += __shfl_xor(v, 8);
        if (n == 0) atomicAdd(&sS[q * 4 + r], v);
    }
    float* Yc = Yp + c * 131072;
#pragma unroll
    for (int nsl = 0; nsl < 2; ++nsl) {
        int ns = wave * 2 + nsl;
#pragma unroll
        for (int r = 0; r < 4; ++r)
            Yc[(i0 + q * 4 + r) * 128 + ns * 16 + n] = accB[nsl][r];
    }
    __syncthreads();
    if (t < 16) Sp[c * 1024 + i0 + t] = sS[t];
}

// ---------------- kernel 3: sum partials + expmap ----------------
__global__ __launch_bounds__(256) void hyp_exp(
    const float* __restrict__ x, const float* __restrict__ Yp,
    const float* __restrict__ Sp, const float* __restrict__ st_x2,
    float* __restrict__ out)
{
    int i    = blockIdx.x * 4 + (threadIdx.x >> 6);
    int lane = threadIdx.x & 63;
    float y0 = 0.f, y1 = 0.f, S = 0.f;
#pragma unroll
    for (int cc = 0; cc < 8; ++cc) {
        y0 += Yp[cc * 131072 + i * 128 + lane];
        y1 += Yp[cc * 131072 + i * 128 + 64 + lane];
        S  += Sp[cc * 1024 + i];
    }
    float x0 = x[i * 128 + lane], x1 = x[i * 128 + 64 + lane];
    float x2 = st_x2[i];
    float b  = fmaxf(1.f - x2, 1e-15f);
    float u0 = b * (b * y0 - S * x0);
    float u1 = b * (b * y1 - S * x1);
    float un2 = u0 * u0 + u1 * u1;
    float xu  = x0 * u0 + x1 * u1;
    for (int m = 1; m < 64; m <<= 1) {
        un2 += __shfl_xor(un2, m);
        xu  += __shfl_xor(xu, m);
    }
    float un  = sqrtf(fmaxf(un2, 1e-15f));
    float e2  = __expf(2.f * un * rcpf(b));
    float th  = 1.f - 2.f * rcpf(e2 + 1.f);   // tanh(un/b)
    float s2  = th * rcpf(un);                 // tanh(un/b)/un
    float xy  = s2 * xu;                       // <x, second>
    float y2s = th * th;                       // ||second||^2
    float coef = 1.f + 2.f * xy + y2s;
    float den  = fmaxf(1.f + 2.f * xy + x2 * y2s, 1e-15f);
    float rd   = rcpf(den);
    out[i * 128 + lane]      = (coef * x0 + b * (s2 * u0)) * rd;
    out[i * 128 + 64 + lane] = (coef * x1 + b * (s2 * u1)) * rd;
}

extern "C" void kernel_launch(void* const* d_in, const int* in_sizes, int n_in,
                              void* d_out, int out_size, void* d_ws, size_t ws_size,
                              hipStream_t stream) {
    const float* x    = (const float*)d_in[0];
    const float* adj  = (const float*)d_in[1];
    const float* w    = (const float*)d_in[2];
    const float* batt = (const float*)d_in[3];
    float* out = (float*)d_out;

    float* Yp    = (float*)d_ws;        // 8 * 131072
    float* Sp    = Yp + 8 * 131072;     // 8 * 1024
    float* st_x2 = Sp + 8 * 1024;       // 1024
    float* st_L  = st_x2 + 1024;        // 1024
    float* st_R  = st_L + 1024;         // 1024

    hipLaunchKernelGGL(hyp_stats, dim3(256), dim3(256), 0, stream, x, w, st_x2, st_L, st_R);
    hipLaunchKernelGGL(hyp_main, dim3(64, 8), dim3(256), 0, stream,
                       x, adj, batt, st_x2, st_L, st_R, Yp, Sp);
    hipLaunchKernelGGL(hyp_exp, dim3(256), dim3(256), 0, stream, x, Yp, Sp, st_x2, out);
}